// Round 11
// baseline (597.823 us; speedup 1.0000x reference)
//
#include <hip/hip_runtime.h>
#include <cstdint>
#include <cstddef>

// ---------------- problem constants ----------------
#define TTOK 8192          // B*S tokens
#define HDIM 1024
#define IDIM 4096
#define NEXP 8
#define PMAX 18432         // 16384 + 8*256 (segment padding to 256)
#define WS_NEED 302260352ULL

// GEMM geometry (both): 256(wt/hcol) x 256(tok) block, BK=32, 512 thr
// (8 waves = 2 weight-halves x 4 token-quarters), wave tile 128x64,
// ring-3 of 32KB slots (A 16KB + B 16KB) = 96KB, 1 block/CU.
#define SLOTG 32768

typedef __attribute__((ext_vector_type(8))) short bf16x8;
typedef __attribute__((ext_vector_type(4))) float f32x4;

#define AS3 __attribute__((address_space(3)))
#define AS1 __attribute__((address_space(1)))

__device__ __forceinline__ void gld16(const void* g, void* s) {
  // async global->LDS, 16B/lane; LDS dest is wave-uniform base (+lane*16 in HW)
  __builtin_amdgcn_global_load_lds((const AS1 void*)g, (AS3 void*)s, 16, 0, 0);
}

// s_barrier pinned against compiler code motion (raw s_barrier is NOT an IR
// memory fence; sched_barrier(0) forbids any instruction crossing it)
__device__ __forceinline__ void pinned_barrier() {
  __builtin_amdgcn_sched_barrier(0);
  __builtin_amdgcn_s_barrier();
  __builtin_amdgcn_sched_barrier(0);
}

__device__ __forceinline__ void wait_lds() {
  asm volatile("s_waitcnt lgkmcnt(0)" ::: "memory");
  __builtin_amdgcn_sched_barrier(0);   // rule 18: MFMA must not hoist above
}

__device__ __forceinline__ unsigned short f2b(float f) {
  unsigned u = __builtin_bit_cast(unsigned, f);
  unsigned r = ((u >> 16) & 1u) + 0x7FFFu;   // RNE
  return (unsigned short)((u + r) >> 16);
}

// meta layout (ints): [0..7] counts, [16..23] offs, meta[24]=padded total
// ---------------- router: logits, top2, x->bf16 (no atomics) ----------------
__global__ __launch_bounds__(256, 2) void router_k(
    const float* __restrict__ x, const float* __restrict__ wr,
    unsigned short* __restrict__ xb, int* __restrict__ t2e,
    float* __restrict__ t2w)
{
  const int t = blockIdx.x * 4 + (threadIdx.x >> 6);
  const int l = threadIdx.x & 63;
  const float* xr = x + (size_t)t * HDIM;
  float acc[8] = {0.f,0.f,0.f,0.f,0.f,0.f,0.f,0.f};
  #pragma unroll
  for (int j = 0; j < 4; ++j) {
    const int base = j * 256 + l * 4;
    const float4 xv = *(const float4*)(xr + base);
    const float xa[4] = {xv.x, xv.y, xv.z, xv.w};
    ushort4 ub;
    ub.x = f2b(xa[0]); ub.y = f2b(xa[1]); ub.z = f2b(xa[2]); ub.w = f2b(xa[3]);
    *(ushort4*)(xb + (size_t)t * HDIM + base) = ub;
    #pragma unroll
    for (int ii = 0; ii < 4; ++ii) {
      const float4 w0 = *(const float4*)(wr + (size_t)(base + ii) * 8);
      const float4 w1 = *(const float4*)(wr + (size_t)(base + ii) * 8 + 4);
      acc[0] += xa[ii] * w0.x; acc[1] += xa[ii] * w0.y;
      acc[2] += xa[ii] * w0.z; acc[3] += xa[ii] * w0.w;
      acc[4] += xa[ii] * w1.x; acc[5] += xa[ii] * w1.y;
      acc[6] += xa[ii] * w1.z; acc[7] += xa[ii] * w1.w;
    }
  }
  #pragma unroll
  for (int e = 0; e < 8; ++e) {
    float v = acc[e];
    #pragma unroll
    for (int off = 32; off > 0; off >>= 1) v += __shfl_xor(v, off);
    acc[e] = v;
  }
  if (l == 0) {
    float l0 = -1e30f; int i0 = 0;
    #pragma unroll
    for (int e = 0; e < 8; ++e) if (acc[e] > l0) { l0 = acc[e]; i0 = e; }
    float l1 = -1e30f; int i1 = (i0 == 0) ? 1 : 0;
    #pragma unroll
    for (int e = 0; e < 8; ++e) if (e != i0 && acc[e] > l1) { l1 = acc[e]; i1 = e; }
    // renormalized top2 softmax == sigmoid of gap
    const float w0 = 1.f / (1.f + expf(l1 - l0));
    t2e[t * 2] = i0; t2e[t * 2 + 1] = i1;
    t2w[t * 2] = w0; t2w[t * 2 + 1] = 1.f - w0;
  }
}

// ---------------- count: ballot histogram, offsets (1 block, no atomics) ----
__global__ void count_k(const int* __restrict__ t2e, int* __restrict__ meta) {
  const int t = threadIdx.x, w = t >> 6, l = t & 63;
  int cnt[8] = {0,0,0,0,0,0,0,0};
  for (int c = 0; c < 16; ++c) {               // 8 waves x 16 x 64 = 8192
    const int tok = (w * 16 + c) * 64 + l;
    const int e0 = t2e[2 * tok], e1 = t2e[2 * tok + 1];
    #pragma unroll
    for (int e = 0; e < 8; ++e)
      cnt[e] += __popcll(__ballot(e0 == e)) + __popcll(__ballot(e1 == e));
  }
  __shared__ int part[8][8];
  if (l == 0) {
    #pragma unroll
    for (int e = 0; e < 8; ++e) part[w][e] = cnt[e];
  }
  __syncthreads();
  if (t == 0) {
    int off = 0;
    #pragma unroll
    for (int e = 0; e < 8; ++e) {
      int s = 0;
      #pragma unroll
      for (int w2 = 0; w2 < 8; ++w2) s += part[w2][e];
      meta[e] = s; meta[16 + e] = off; off += (s + 255) & ~255;
    }
    meta[24] = off;
  }
}

// ---------------- scatter: deterministic per-expert prefix scan -------------
__global__ void scatter_k(const int* __restrict__ t2e, const int* __restrict__ meta,
                          int* __restrict__ ltok, int* __restrict__ t2p)
{
  const int e = blockIdx.x;
  const int t = threadIdx.x, w = t >> 6, l = t & 63;
  const int off = meta[16 + e];
  const int cnt = meta[e];
  __shared__ int wsum[4];
  __shared__ int base;
  if (t == 0) base = 0;
  __syncthreads();
  const unsigned long long lt = (1ULL << l) - 1ULL;
  for (int c = 0; c < TTOK / 256; ++c) {
    const int tok = c * 256 + t;
    const bool m0 = (t2e[2 * tok] == e);
    const bool m1 = (t2e[2 * tok + 1] == e);
    const unsigned long long b0 = __ballot(m0);
    const unsigned long long b1 = __ballot(m1);
    const int n0 = __popcll(b0), n1 = __popcll(b1);
    const int r0 = __popcll(b0 & lt);
    const int r1 = n0 + __popcll(b1 & lt);
    if (l == 0) wsum[w] = n0 + n1;
    __syncthreads();
    int wb = base;
    #pragma unroll
    for (int i = 0; i < 4; ++i) if (i < w) wb += wsum[i];
    const int tot = wsum[0] + wsum[1] + wsum[2] + wsum[3];
    __syncthreads();
    if (t == 0) base += tot;
    if (m0) { const int p = off + wb + r0; ltok[p] = tok; t2p[2 * tok] = p; }
    if (m1) { const int p = off + wb + r1; ltok[p] = tok; t2p[2 * tok + 1] = p; }
    __syncthreads();
  }
  const int padded = (cnt + 255) & ~255;
  for (int i = cnt + t; i < padded; i += 256) ltok[off + i] = -1;
}

// ---------------- transpose-pack W[e][K][N] fp32 -> WT[e][N][K] bf16 ----------------
__global__ __launch_bounds__(256, 2) void packT_k(const float* __restrict__ src,
                                                  unsigned short* __restrict__ dst,
                                                  int K, int N)
{
  const int tiles_n = N >> 8, tiles_k = K >> 5;
  const int bid = blockIdx.x;
  const int e = bid / (tiles_k * tiles_n);
  const int rem = bid % (tiles_k * tiles_n);
  const int kt = rem / tiles_n, it = rem % tiles_n;
  const float* S = src + (size_t)e * K * N + (size_t)kt * 32 * N + (size_t)it * 256;
  unsigned short* D = dst + (size_t)e * N * K + (size_t)it * 256 * K + (size_t)kt * 32;
  __shared__ uint32_t lds[256 * 17];
  const int t = threadIdx.x;
  #pragma unroll
  for (int q = 0; q < 4; ++q) {
    const int task = q * 256 + t;
    const int i4 = task & 63, kp = task >> 6;
    const float* p0 = S + (size_t)(2 * kp) * N + i4 * 4;
    const float4 r0 = *(const float4*)p0;
    const float4 r1 = *(const float4*)(p0 + N);
    const float a0[4] = {r0.x, r0.y, r0.z, r0.w};
    const float a1[4] = {r1.x, r1.y, r1.z, r1.w};
    #pragma unroll
    for (int j = 0; j < 4; ++j)
      lds[(i4 * 4 + j) * 17 + kp] = (uint32_t)f2b(a0[j]) | ((uint32_t)f2b(a1[j]) << 16);
  }
  __syncthreads();
  #pragma unroll
  for (int r = 0; r < 4; ++r) {
    const int idx = r * 256 + t;
    const int il = idx >> 2, q4 = idx & 3;
    uint4 o;
    o.x = lds[il * 17 + q4 * 4 + 0];
    o.y = lds[il * 17 + q4 * 4 + 1];
    o.z = lds[il * 17 + q4 * 4 + 2];
    o.w = lds[il * 17 + q4 * 4 + 3];
    *(uint4*)(D + (size_t)il * K + q4 * 8) = o;
  }
}

// ===== grouped GEMM, 256x256 block, 8 waves (wave tile 128x64), BK=32, =====
// ===== ring-3, m201-style 2-phase-per-K-tile schedule                  =====
// LDS swizzle (bijective, verified rounds 2-10, bank-conflict==0): granule G
// of a 16KB operand region (256 rows x 64B) maps to (row,g): line=G>>3,
// q=(G&7)^(line&7), row=2*line+(q>>2), g=q&3. Stage keeps LDS dest linear
// (gld16) with inverse-swizzled global source; reads use line=row>>1,
// p=((row&1)*4+g)^(line&7), byte = line*128 + p*16.
// Per K-tile (2 phases, m201 discipline — ds_reads BEFORE the barrier so
// their latency hides under barrier-arrival spread; lgkmcnt(0) after):
//  P0: read af[0..7]+b01 (10 ds_read_b128); stage half0(kt+2) (2 gld16);
//      barrier; lgkmcnt(0); setprio1; 16 MFMA (acc[*][0..1]); setprio0; barrier
//  P1: read b23 (2); stage half1(kt+2); vmcnt(4|0) [never 0 mid-loop];
//      barrier; lgkmcnt(0); setprio1; 16 MFMA (acc[*][2..3]); setprio0; barrier
// Race proof: vmcnt for tile kt+1 retires before the barrier preceding kt+1's
// first ds_read; STAGE(kt+2) writes slot (kt-1)%3 whose reads were consumed
// (lgkmcnt(0)) before the previous tile's closing barrier. sched_barrier(0)
// pins every s_barrier (round-8 lesson).
// vmcnt ledger (4 loads/thread/tile): prologue 8 -> vmcnt(4)+barrier; steady
// P1 vmcnt(4); kt=NT-2 vmcnt(0); kt=NT-1 none.

// ---------------- grouped GEMM1: h = silu(W1T-tile x Xg-tile + b1) -----------
__global__ __launch_bounds__(512, 2) void gemm1_k(
    const unsigned short* __restrict__ xb, const unsigned short* __restrict__ w1t,
    const float* __restrict__ b1, const int* __restrict__ meta,
    const int* __restrict__ ltok, unsigned short* __restrict__ h)
{
  const int wg = blockIdx.x;                       // 1152 = 72*16, %8==0
  const int id = (wg & 7) * (1152 / 8) + (wg >> 3);
  const int mt = id >> 4, nt = id & 15;
  if (mt * 256 >= meta[24]) return;
  int e = 0;
  #pragma unroll
  for (int i = 1; i < 8; ++i) if (meta[16 + i] <= mt * 256) e = i;

  extern __shared__ char lds[];                    // 3 slots x 32KB
  const int t = threadIdx.x;
  const int w = t >> 6, l = t & 63;
  const int wa = w >> 2, wb = w & 3;               // weight-half, token-quarter

  // staging sources (2 granules/thread/operand): G = c*512 + t
  const unsigned short* asrc[2]; const unsigned short* bsrc[2];
  #pragma unroll
  for (int c = 0; c < 2; ++c) {
    const int G = c * 512 + t;
    const int line = G >> 3, q = (G & 7) ^ (line & 7);
    const int row = 2 * line + (q >> 2), g = q & 3;
    asrc[c] = w1t + ((size_t)e * IDIM + nt * 256 + row) * HDIM + g * 8;
    int tok = ltok[mt * 256 + row]; if (tok < 0) tok = 0;
    bsrc[c] = xb + (size_t)tok * HDIM + g * 8;
  }

  const int lr = l & 15, lg = l >> 4;
  f32x4 acc[8][4] = {};

  auto STAGE_H = [&](int kt, int c) {              // one half: 2 gld16
    char* sb = lds + (kt % 3) * SLOTG;
    const int ks = kt * 32;
    gld16(asrc[c] + ks, sb + (c * 512 + w * 64) * 16);
    gld16(bsrc[c] + ks, sb + 16384 + (c * 512 + w * 64) * 16);
  };

  STAGE_H(0, 0); STAGE_H(0, 1); STAGE_H(1, 0); STAGE_H(1, 1);
  asm volatile("s_waitcnt vmcnt(4)" ::: "memory");
  pinned_barrier();

  const int NT = HDIM / 32;                        // 32
  for (int kt = 0; kt < NT; ++kt) {
    const char* sl = lds + (kt % 3) * SLOTG;
    const bool pf = (kt + 2 < NT);
    // ---------- phase 0 ----------
    bf16x8 af[8], b01[2];
    #pragma unroll
    for (int fm = 0; fm < 8; ++fm) {
      const int row = wa * 128 + fm * 16 + lr;
      const int line = row >> 1;
      const int p = (((row & 1) << 2) + lg) ^ (line & 7);
      af[fm] = *(const bf16x8*)(sl + line * 128 + p * 16);
    }
    #pragma unroll
    for (int fn = 0; fn < 2; ++fn) {
      const int row = wb * 64 + fn * 16 + lr;
      const int line = row >> 1;
      const int p = (((row & 1) << 2) + lg) ^ (line & 7);
      b01[fn] = *(const bf16x8*)(sl + 16384 + line * 128 + p * 16);
    }
    if (pf) STAGE_H(kt + 2, 0);
    pinned_barrier();
    wait_lds();
    __builtin_amdgcn_s_setprio(1);
    #pragma unroll
    for (int fm = 0; fm < 8; ++fm)
      #pragma unroll
      for (int fn = 0; fn < 2; ++fn)
        acc[fm][fn] = __builtin_amdgcn_mfma_f32_16x16x32_bf16(af[fm], b01[fn], acc[fm][fn], 0, 0, 0);
    __builtin_amdgcn_s_setprio(0);
    pinned_barrier();
    // ---------- phase 1 ----------
    bf16x8 b23[2];
    #pragma unroll
    for (int fn = 0; fn < 2; ++fn) {
      const int row = wb * 64 + (fn + 2) * 16 + lr;
      const int line = row >> 1;
      const int p = (((row & 1) << 2) + lg) ^ (line & 7);
      b23[fn] = *(const bf16x8*)(sl + 16384 + line * 128 + p * 16);
    }
    if (pf) {
      STAGE_H(kt + 2, 1);
      asm volatile("s_waitcnt vmcnt(4)" ::: "memory");
    } else if (kt + 1 < NT) {
      asm volatile("s_waitcnt vmcnt(0)" ::: "memory");
    }
    pinned_barrier();
    wait_lds();
    __builtin_amdgcn_s_setprio(1);
    #pragma unroll
    for (int fm = 0; fm < 8; ++fm)
      #pragma unroll
      for (int fn = 0; fn < 2; ++fn)
        acc[fm][fn + 2] = __builtin_amdgcn_mfma_f32_16x16x32_bf16(af[fm], b23[fn], acc[fm][fn + 2], 0, 0, 0);
    __builtin_amdgcn_s_setprio(0);
    pinned_barrier();
  }

  // epilogue: +b1, silu, packed ushort4 stores (D reg-dim = i, col-dim = token)
  const int lg4 = lg * 4;
  #pragma unroll
  for (int fm = 0; fm < 8; ++fm) {
    const int ib = nt * 256 + wa * 128 + fm * 16 + lg4;
    const float4 b1v = *(const float4*)(b1 + e * IDIM + ib);
    #pragma unroll
    for (int fn = 0; fn < 4; ++fn) {
      const int trow = mt * 256 + wb * 64 + fn * 16 + lr;
      const float v0 = acc[fm][fn][0] + b1v.x;
      const float v1 = acc[fm][fn][1] + b1v.y;
      const float v2 = acc[fm][fn][2] + b1v.z;
      const float v3 = acc[fm][fn][3] + b1v.w;
      ushort4 st;
      st.x = f2b(v0 / (1.f + __expf(-v0)));
      st.y = f2b(v1 / (1.f + __expf(-v1)));
      st.z = f2b(v2 / (1.f + __expf(-v2)));
      st.w = f2b(v3 / (1.f + __expf(-v3)));
      *(ushort4*)(h + (size_t)trow * IDIM + ib) = st;
    }
  }
}

// ---------------- grouped GEMM2: y = h @ W2T^T (float4 stores) ----------------
__global__ __launch_bounds__(512, 2) void gemm2_k(
    const unsigned short* __restrict__ h, const unsigned short* __restrict__ w2t,
    const int* __restrict__ meta, float* __restrict__ y)
{
  const int wg = blockIdx.x;                       // 288 = 72*4, %8==0
  const int id = (wg & 7) * (288 / 8) + (wg >> 3);
  const int mt = id >> 2, nt = id & 3;
  if (mt * 256 >= meta[24]) return;
  int e = 0;
  #pragma unroll
  for (int i = 1; i < 8; ++i) if (meta[16 + i] <= mt * 256) e = i;

  extern __shared__ char lds[];
  const int t = threadIdx.x;
  const int w = t >> 6, l = t & 63;
  const int wa = w >> 2, wb = w & 3;

  // A = W2T rows (hcol-dim, nt tile); B = h token rows (mt tile)
  const unsigned short* asrc[2]; const unsigned short* bsrc[2];
  #pragma unroll
  for (int c = 0; c < 2; ++c) {
    const int G = c * 512 + t;
    const int line = G >> 3, q = (G & 7) ^ (line & 7);
    const int row = 2 * line + (q >> 2), g = q & 3;
    asrc[c] = w2t + ((size_t)e * HDIM + nt * 256 + row) * IDIM + g * 8;
    bsrc[c] = h + (size_t)(mt * 256 + row) * IDIM + g * 8;
  }

  const int lr = l & 15, lg = l >> 4;
  f32x4 acc[8][4] = {};

  auto STAGE_H = [&](int kt, int c) {
    char* sb = lds + (kt % 3) * SLOTG;
    const int ks = kt * 32;
    gld16(asrc[c] + ks, sb + (c * 512 + w * 64) * 16);
    gld16(bsrc[c] + ks, sb + 16384 + (c * 512 + w * 64) * 16);
  };

  STAGE_H(0, 0); STAGE_H(0, 1); STAGE_H(1, 0); STAGE_H(1, 1);
  asm volatile("s_waitcnt vmcnt(4)" ::: "memory");
  pinned_barrier();

  const int NT = IDIM / 32;                        // 128
  for (int kt = 0; kt < NT; ++kt) {
    const char* sl = lds + (kt % 3) * SLOTG;
    const bool pf = (kt + 2 < NT);
    // ---------- phase 0 ----------
    bf16x8 af[8], b01[2];
    #pragma unroll
    for (int fm = 0; fm < 8; ++fm) {
      const int row = wa * 128 + fm * 16 + lr;
      const int line = row >> 1;
      const int p = (((row & 1) << 2) + lg) ^ (line & 7);
      af[fm] = *(const bf16x8*)(sl + line * 128 + p * 16);
    }
    #pragma unroll
    for (int fn = 0; fn < 2; ++fn) {
      const int row = wb * 64 + fn * 16 + lr;
      const int line = row >> 1;
      const int p = (((row & 1) << 2) + lg) ^ (line & 7);
      b01[fn] = *(const bf16x8*)(sl + 16384 + line * 128 + p * 16);
    }
    if (pf) STAGE_H(kt + 2, 0);
    pinned_barrier();
    wait_lds();
    __builtin_amdgcn_s_setprio(1);
    #pragma unroll
    for (int fm = 0; fm < 8; ++fm)
      #pragma unroll
      for (int fn = 0; fn < 2; ++fn)
        acc[fm][fn] = __builtin_amdgcn_mfma_f32_16x16x32_bf16(af[fm], b01[fn], acc[fm][fn], 0, 0, 0);
    __builtin_amdgcn_s_setprio(0);
    pinned_barrier();
    // ---------- phase 1 ----------
    bf16x8 b23[2];
    #pragma unroll
    for (int fn = 0; fn < 2; ++fn) {
      const int row = wb * 64 + (fn + 2) * 16 + lr;
      const int line = row >> 1;
      const int p = (((row & 1) << 2) + lg) ^ (line & 7);
      b23[fn] = *(const bf16x8*)(sl + 16384 + line * 128 + p * 16);
    }
    if (pf) {
      STAGE_H(kt + 2, 1);
      asm volatile("s_waitcnt vmcnt(4)" ::: "memory");
    } else if (kt + 1 < NT) {
      asm volatile("s_waitcnt vmcnt(0)" ::: "memory");
    }
    pinned_barrier();
    wait_lds();
    __builtin_amdgcn_s_setprio(1);
    #pragma unroll
    for (int fm = 0; fm < 8; ++fm)
      #pragma unroll
      for (int fn = 0; fn < 2; ++fn)
        acc[fm][fn + 2] = __builtin_amdgcn_mfma_f32_16x16x32_bf16(af[fm], b23[fn], acc[fm][fn + 2], 0, 0, 0);
    __builtin_amdgcn_s_setprio(0);
    pinned_barrier();
  }

  // epilogue: coalesced float4 stores (D reg-dim = hcol, col-dim = token)
  const int lg4 = lg * 4;
  #pragma unroll
  for (int fm = 0; fm < 8; ++fm) {
    const int colb = nt * 256 + wa * 128 + fm * 16 + lg4;
    #pragma unroll
    for (int fn = 0; fn < 4; ++fn) {
      const int row = mt * 256 + wb * 64 + fn * 16 + lr;
      float4 st;
      st.x = acc[fm][fn][0]; st.y = acc[fm][fn][1];
      st.z = acc[fm][fn][2]; st.w = acc[fm][fn][3];
      *(float4*)(y + (size_t)row * HDIM + colb) = st;
    }
  }
}

// ---------------- combine: out[t] = w0*(y[p0]+b2[e0]) + w1*(y[p1]+b2[e1]) ----------------
__global__ __launch_bounds__(256, 4) void combine_k(
    const float* __restrict__ y, const float* __restrict__ b2,
    const int* __restrict__ t2e, const float* __restrict__ t2w,
    const int* __restrict__ t2p, float* __restrict__ out)
{
  const int t = blockIdx.x * 4 + (threadIdx.x >> 6);
  const int l = threadIdx.x & 63;
  const int e0 = t2e[t * 2], e1 = t2e[t * 2 + 1];
  const float w0 = t2w[t * 2], w1v = t2w[t * 2 + 1];
  const int p0 = t2p[t * 2], p1 = t2p[t * 2 + 1];
  const float* y0 = y + (size_t)p0 * HDIM;
  const float* y1 = y + (size_t)p1 * HDIM;
  const float* bb0 = b2 + e0 * HDIM;
  const float* bb1 = b2 + e1 * HDIM;
  float* o = out + (size_t)t * HDIM;
  #pragma unroll
  for (int j = 0; j < 4; ++j) {
    const int c = j * 256 + l * 4;
    const float4 a = *(const float4*)(y0 + c);
    const float4 b = *(const float4*)(y1 + c);
    const float4 c0 = *(const float4*)(bb0 + c);
    const float4 c1 = *(const float4*)(bb1 + c);
    float4 r;
    r.x = w0 * (a.x + c0.x) + w1v * (b.x + c1.x);
    r.y = w0 * (a.y + c0.y) + w1v * (b.y + c1.y);
    r.z = w0 * (a.z + c0.z) + w1v * (b.z + c1.z);
    r.w = w0 * (a.w + c0.w) + w1v * (b.w + c1.w);
    *(float4*)(o + c) = r;
  }
}

__global__ void sentinel_k(float* out) { out[0] = 1.0e6f; }

// ---------------- launcher ----------------
extern "C" void kernel_launch(void* const* d_in, const int* in_sizes, int n_in,
                              void* d_out, int out_size, void* d_ws, size_t ws_size,
                              hipStream_t stream)
{
  (void)in_sizes; (void)n_in; (void)out_size;
  const float* x  = (const float*)d_in[0];
  const float* wr = (const float*)d_in[1];
  const float* w1 = (const float*)d_in[2];
  const float* b1 = (const float*)d_in[3];
  const float* w2 = (const float*)d_in[4];
  const float* b2 = (const float*)d_in[5];
  float* out = (float*)d_out;
  char* ws = (char*)d_ws;

  if (ws_size < WS_NEED) { sentinel_k<<<1, 1, 0, stream>>>(out); return; }

  unsigned short* xb  = (unsigned short*)(ws);                 // 16.78 MB
  unsigned short* w1t = (unsigned short*)(ws + 16777216);      // 67.1 MB
  unsigned short* w2t = (unsigned short*)(ws + 83886080);      // 67.1 MB
  unsigned short* h   = (unsigned short*)(ws + 150994944);     // 151.0 MB
  int*   t2e  = (int*)(ws + 301989888);
  float* t2w  = (float*)(ws + 302055424);
  int*   ltok = (int*)(ws + 302120960);
  int*   t2p  = (int*)(ws + 302194688);
  int*   meta = (int*)(ws + 302260224);
  // y aliases xb+w1t (both dead after gemm1): PMAX*HDIM*4 = 75.5MB < 83.9MB
  float* y    = (float*)(ws);

  // allow 96KB dynamic LDS on the GEMMs (non-stream op; graph-capture safe)
  hipFuncSetAttribute((const void*)gemm1_k, hipFuncAttributeMaxDynamicSharedMemorySize, 3 * SLOTG);
  hipFuncSetAttribute((const void*)gemm2_k, hipFuncAttributeMaxDynamicSharedMemorySize, 3 * SLOTG);

  router_k<<<TTOK / 4, 256, 0, stream>>>(x, wr, xb, t2e, t2w);
  packT_k<<<NEXP * (HDIM / 32) * (IDIM / 256), 256, 0, stream>>>(w1, w1t, HDIM, IDIM);
  packT_k<<<NEXP * (IDIM / 32) * (HDIM / 256), 256, 0, stream>>>(w2, w2t, IDIM, HDIM);
  count_k<<<1, 512, 0, stream>>>(t2e, meta);
  scatter_k<<<NEXP, 256, 0, stream>>>(t2e, meta, ltok, t2p);

  gemm1_k<<<72 * 16, 512, 3 * SLOTG, stream>>>(xb, w1t, b1, meta, ltok, h);
  gemm2_k<<<72 * 4, 512, 3 * SLOTG, stream>>>(h, w2t, meta, y);
  combine_k<<<TTOK / 4, 256, 0, stream>>>(y, b2, t2e, t2w, t2p, out);
}

// Round 12
// 532.640 us; speedup vs baseline: 1.1224x; 1.1224x over previous
//
#include <hip/hip_runtime.h>
#include <cstdint>
#include <cstddef>

// ---------------- problem constants ----------------
#define TTOK 8192          // B*S tokens
#define HDIM 1024
#define IDIM 4096
#define NEXP 8
#define PMAX 18432         // 16384 + 8*256 (segment padding to 256)
#define WS_NEED 302260352ULL

// gemm1: 256(tok) x 128(wt) block, BK=32, 512 thr, ring-3 24KB slots (72KB).
// gemm2: 128x128 block, BK=32, 256 thr, ring-3 16KB slots (48KB).
#define SLOT1 24576
#define SLOT2 16384

typedef __attribute__((ext_vector_type(8))) short bf16x8;
typedef __attribute__((ext_vector_type(4))) float f32x4;

#define AS3 __attribute__((address_space(3)))
#define AS1 __attribute__((address_space(1)))

__device__ __forceinline__ void gld16(const void* g, void* s) {
  // async global->LDS, 16B/lane; LDS dest is wave-uniform base (+lane*16 in HW)
  __builtin_amdgcn_global_load_lds((const AS1 void*)g, (AS3 void*)s, 16, 0, 0);
}

// barrier pinned against compiler code motion (raw s_barrier is NOT an IR
// memory fence; sched_barrier(0) forbids any instruction crossing it)
__device__ __forceinline__ void pinned_barrier() {
  __builtin_amdgcn_sched_barrier(0);
  __builtin_amdgcn_s_barrier();
  __builtin_amdgcn_sched_barrier(0);
}

__device__ __forceinline__ unsigned short f2b(float f) {
  unsigned u = __builtin_bit_cast(unsigned, f);
  unsigned r = ((u >> 16) & 1u) + 0x7FFFu;   // RNE
  return (unsigned short)((u + r) >> 16);
}

__device__ __forceinline__ float b2f(unsigned short u) {
  return __builtin_bit_cast(float, ((unsigned)u) << 16);
}

// meta layout (ints): [0..7] counts, [16..23] offs, meta[24]=padded total

// ---------------- merged prep: router + packT(w1) + packT(w2) ----------------
// blocks [0,2048): router (4 tokens/block); [2048,6144): packT w1;
// [6144,10240): packT w2. All independent -> concurrent in one dispatch.
__device__ __forceinline__ void router_body(
    int bid, int t, const float* __restrict__ x, const float* __restrict__ wr,
    unsigned short* __restrict__ xb, int* __restrict__ t2e,
    float* __restrict__ t2w)
{
  const int tok = bid * 4 + (t >> 6);
  const int l = t & 63;
  const float* xr = x + (size_t)tok * HDIM;
  float acc[8] = {0.f,0.f,0.f,0.f,0.f,0.f,0.f,0.f};
  #pragma unroll
  for (int j = 0; j < 4; ++j) {
    const int base = j * 256 + l * 4;
    const float4 xv = *(const float4*)(xr + base);
    const float xa[4] = {xv.x, xv.y, xv.z, xv.w};
    ushort4 ub;
    ub.x = f2b(xa[0]); ub.y = f2b(xa[1]); ub.z = f2b(xa[2]); ub.w = f2b(xa[3]);
    *(ushort4*)(xb + (size_t)tok * HDIM + base) = ub;
    #pragma unroll
    for (int ii = 0; ii < 4; ++ii) {
      const float4 w0 = *(const float4*)(wr + (size_t)(base + ii) * 8);
      const float4 w1 = *(const float4*)(wr + (size_t)(base + ii) * 8 + 4);
      acc[0] += xa[ii] * w0.x; acc[1] += xa[ii] * w0.y;
      acc[2] += xa[ii] * w0.z; acc[3] += xa[ii] * w0.w;
      acc[4] += xa[ii] * w1.x; acc[5] += xa[ii] * w1.y;
      acc[6] += xa[ii] * w1.z; acc[7] += xa[ii] * w1.w;
    }
  }
  #pragma unroll
  for (int e = 0; e < 8; ++e) {
    float v = acc[e];
    #pragma unroll
    for (int off = 32; off > 0; off >>= 1) v += __shfl_xor(v, off);
    acc[e] = v;
  }
  if (l == 0) {
    float l0 = -1e30f; int i0 = 0;
    #pragma unroll
    for (int e = 0; e < 8; ++e) if (acc[e] > l0) { l0 = acc[e]; i0 = e; }
    float l1 = -1e30f; int i1 = (i0 == 0) ? 1 : 0;
    #pragma unroll
    for (int e = 0; e < 8; ++e) if (e != i0 && acc[e] > l1) { l1 = acc[e]; i1 = e; }
    // renormalized top2 softmax == sigmoid of gap
    const float w0 = 1.f / (1.f + expf(l1 - l0));
    t2e[tok * 2] = i0; t2e[tok * 2 + 1] = i1;
    t2w[tok * 2] = w0; t2w[tok * 2 + 1] = 1.f - w0;
  }
}

__device__ __forceinline__ void packT_body(
    int bid, int t, uint32_t* __restrict__ plds,
    const float* __restrict__ src, unsigned short* __restrict__ dst,
    int K, int N)
{
  const int tiles_n = N >> 8, tiles_k = K >> 5;
  const int e = bid / (tiles_k * tiles_n);
  const int rem = bid % (tiles_k * tiles_n);
  const int kt = rem / tiles_n, it = rem % tiles_n;
  const float* S = src + (size_t)e * K * N + (size_t)kt * 32 * N + (size_t)it * 256;
  unsigned short* D = dst + (size_t)e * N * K + (size_t)it * 256 * K + (size_t)kt * 32;
  #pragma unroll
  for (int q = 0; q < 4; ++q) {
    const int task = q * 256 + t;
    const int i4 = task & 63, kp = task >> 6;
    const float* p0 = S + (size_t)(2 * kp) * N + i4 * 4;
    const float4 r0 = *(const float4*)p0;
    const float4 r1 = *(const float4*)(p0 + N);
    const float a0[4] = {r0.x, r0.y, r0.z, r0.w};
    const float a1[4] = {r1.x, r1.y, r1.z, r1.w};
    #pragma unroll
    for (int j = 0; j < 4; ++j)
      plds[(i4 * 4 + j) * 17 + kp] = (uint32_t)f2b(a0[j]) | ((uint32_t)f2b(a1[j]) << 16);
  }
  __syncthreads();
  #pragma unroll
  for (int r = 0; r < 4; ++r) {
    const int idx = r * 256 + t;
    const int il = idx >> 2, q4 = idx & 3;
    uint4 o;
    o.x = plds[il * 17 + q4 * 4 + 0];
    o.y = plds[il * 17 + q4 * 4 + 1];
    o.z = plds[il * 17 + q4 * 4 + 2];
    o.w = plds[il * 17 + q4 * 4 + 3];
    *(uint4*)(D + (size_t)il * K + q4 * 8) = o;
  }
}

__global__ __launch_bounds__(256, 2) void prep_k(
    const float* __restrict__ x, const float* __restrict__ wr,
    unsigned short* __restrict__ xb, int* __restrict__ t2e,
    float* __restrict__ t2w,
    const float* __restrict__ w1, unsigned short* __restrict__ w1t,
    const float* __restrict__ w2, unsigned short* __restrict__ w2t)
{
  __shared__ uint32_t plds[256 * 17];
  const int bid = blockIdx.x, t = threadIdx.x;
  if (bid < 2048) {
    router_body(bid, t, x, wr, xb, t2e, t2w);
  } else if (bid < 2048 + 4096) {
    packT_body(bid - 2048, t, plds, w1, w1t, HDIM, IDIM);
  } else {
    packT_body(bid - 6144, t, plds, w2, w2t, IDIM, HDIM);
  }
}

// ---------------- count: ballot histogram, offsets (1 block, no atomics) ----
__global__ void count_k(const int* __restrict__ t2e, int* __restrict__ meta) {
  const int t = threadIdx.x, w = t >> 6, l = t & 63;
  int cnt[8] = {0,0,0,0,0,0,0,0};
  for (int c = 0; c < 16; ++c) {               // 8 waves x 16 x 64 = 8192
    const int tok = (w * 16 + c) * 64 + l;
    const int e0 = t2e[2 * tok], e1 = t2e[2 * tok + 1];
    #pragma unroll
    for (int e = 0; e < 8; ++e)
      cnt[e] += __popcll(__ballot(e0 == e)) + __popcll(__ballot(e1 == e));
  }
  __shared__ int part[8][8];
  if (l == 0) {
    #pragma unroll
    for (int e = 0; e < 8; ++e) part[w][e] = cnt[e];
  }
  __syncthreads();
  if (t == 0) {
    int off = 0;
    #pragma unroll
    for (int e = 0; e < 8; ++e) {
      int s = 0;
      #pragma unroll
      for (int w2 = 0; w2 < 8; ++w2) s += part[w2][e];
      meta[e] = s; meta[16 + e] = off; off += (s + 255) & ~255;
    }
    meta[24] = off;
  }
}

// ---------------- scatter: deterministic per-expert prefix scan -------------
__global__ void scatter_k(const int* __restrict__ t2e, const int* __restrict__ meta,
                          int* __restrict__ ltok, int* __restrict__ t2p)
{
  const int e = blockIdx.x;
  const int t = threadIdx.x, w = t >> 6, l = t & 63;
  const int off = meta[16 + e];
  const int cnt = meta[e];
  __shared__ int wsum[4];
  __shared__ int base;
  if (t == 0) base = 0;
  __syncthreads();
  const unsigned long long lt = (1ULL << l) - 1ULL;
  for (int c = 0; c < TTOK / 256; ++c) {
    const int tok = c * 256 + t;
    const bool m0 = (t2e[2 * tok] == e);
    const bool m1 = (t2e[2 * tok + 1] == e);
    const unsigned long long b0 = __ballot(m0);
    const unsigned long long b1 = __ballot(m1);
    const int n0 = __popcll(b0), n1 = __popcll(b1);
    const int r0 = __popcll(b0 & lt);
    const int r1 = n0 + __popcll(b1 & lt);
    if (l == 0) wsum[w] = n0 + n1;
    __syncthreads();
    int wb = base;
    #pragma unroll
    for (int i = 0; i < 4; ++i) if (i < w) wb += wsum[i];
    const int tot = wsum[0] + wsum[1] + wsum[2] + wsum[3];
    __syncthreads();
    if (t == 0) base += tot;
    if (m0) { const int p = off + wb + r0; ltok[p] = tok; t2p[2 * tok] = p; }
    if (m1) { const int p = off + wb + r1; ltok[p] = tok; t2p[2 * tok + 1] = p; }
    __syncthreads();
  }
  const int padded = (cnt + 255) & ~255;
  for (int i = cnt + t; i < padded; i += 256) ltok[off + i] = -1;
}

// LDS swizzle (bijective, verified rounds 2-10, bank-conflict==0): granule G of
// an operand region maps to (row,g): line=G>>3, q=(G&7)^(line&7),
// row=2*line+(q>>2), g=q&3. Stage keeps LDS dest linear (gld16) with
// inverse-swizzled global source; reads use line=row>>1,
// p=((row&1)*4+g)^(line&7), byte = line*128 + p*16.
// Race-safe schedule per K-tile (round-9/10 proven):
//   vmcnt(L | 0-at-tail); pinned barrier; ds_reads(slot kt); STAGE(kt+2);
//   setprio(1); MFMA; setprio(0); pinned barrier.

// ---------------- grouped GEMM1: h = silu(W1T-tile x Xg-tile + b1) -----------
// 256(tok) x 128(wt) block, 512 thr (8 waves = 2 wt-halves x 4 tok-quarters),
// wave tile 64x64. Slot: A 8KB @ +0 (128 rows), B 16KB @ +8192 (256 rows).
// 3 loads/thread/stage -> steady vmcnt(3).
__global__ __launch_bounds__(512, 4) void gemm1_k(
    const unsigned short* __restrict__ xb, const unsigned short* __restrict__ w1t,
    const float* __restrict__ b1, const int* __restrict__ meta,
    const int* __restrict__ ltok, unsigned short* __restrict__ h)
{
  const int wg = blockIdx.x;                       // 2304 = 72*32, %8==0
  const int id = (wg & 7) * (2304 / 8) + (wg >> 3);
  const int mt = id >> 5, nt = id & 31;
  if (mt * 256 >= meta[24]) return;
  int e = 0;
  #pragma unroll
  for (int i = 1; i < 8; ++i) if (meta[16 + i] <= mt * 256) e = i;

  extern __shared__ char lds[];                    // 3 slots x 24KB
  const int t = threadIdx.x;
  const int w = t >> 6, l = t & 63;
  const int wn = w & 1, wm = w >> 1;               // weight-half, token-quarter

  // A source (1 granule/thread): G = t (W1T rows = i-dim, nt tile, 128 rows)
  const unsigned short* asrc;
  {
    const int G = t;
    const int line = G >> 3, q = (G & 7) ^ (line & 7);
    const int row = 2 * line + (q >> 2), g = q & 3;
    asrc = w1t + ((size_t)e * IDIM + nt * 128 + row) * HDIM + g * 8;
  }
  // B sources (2 granules/thread): G = c*512 + t (gathered tokens, 256 rows)
  const unsigned short* bsrc[2];
  #pragma unroll
  for (int c = 0; c < 2; ++c) {
    const int G = c * 512 + t;
    const int line = G >> 3, q = (G & 7) ^ (line & 7);
    const int row = 2 * line + (q >> 2), g = q & 3;
    int tok = ltok[mt * 256 + row]; if (tok < 0) tok = 0;
    bsrc[c] = xb + (size_t)tok * HDIM + g * 8;
  }

  const int lr = l & 15, lg = l >> 4;
  f32x4 acc[4][4] = {};

  auto STAGE = [&](int kt) {
    char* sb = lds + (kt % 3) * SLOT1;
    const int ks = kt * 32;
    gld16(asrc + ks, sb + w * 1024);
    gld16(bsrc[0] + ks, sb + 8192 + w * 1024);
    gld16(bsrc[1] + ks, sb + 16384 + w * 1024);
  };

  STAGE(0); STAGE(1);
  const int NT = HDIM / 32;                        // 32
  for (int kt = 0; kt < NT; ++kt) {
    if (kt + 1 < NT) {
      asm volatile("s_waitcnt vmcnt(3)" ::: "memory");
    } else {
      asm volatile("s_waitcnt vmcnt(0)" ::: "memory");
    }
    pinned_barrier();
    const char* sl = lds + (kt % 3) * SLOT1;
    bf16x8 af[4], bf[4];
    #pragma unroll
    for (int f = 0; f < 4; ++f) {
      const int rowA = wn * 64 + f * 16 + lr;
      const int lineA = rowA >> 1;
      const int pA = (((rowA & 1) << 2) + lg) ^ (lineA & 7);
      af[f] = *(const bf16x8*)(sl + lineA * 128 + pA * 16);
      const int rowB = wm * 64 + f * 16 + lr;
      const int lineB = rowB >> 1;
      const int pB = (((rowB & 1) << 2) + lg) ^ (lineB & 7);
      bf[f] = *(const bf16x8*)(sl + 8192 + lineB * 128 + pB * 16);
    }
    if (kt + 2 < NT) STAGE(kt + 2);
    __builtin_amdgcn_s_setprio(1);
    #pragma unroll
    for (int fm = 0; fm < 4; ++fm)
      #pragma unroll
      for (int fn = 0; fn < 4; ++fn)
        acc[fm][fn] = __builtin_amdgcn_mfma_f32_16x16x32_bf16(af[fm], bf[fn], acc[fm][fn], 0, 0, 0);
    __builtin_amdgcn_s_setprio(0);
    pinned_barrier();
  }

  // epilogue: +b1, silu, packed ushort4 stores (D reg-dim = i, col-dim = token)
  const int lg4 = lg * 4;
  #pragma unroll
  for (int fm = 0; fm < 4; ++fm) {
    const int ib = nt * 128 + wn * 64 + fm * 16 + lg4;
    const float4 b1v = *(const float4*)(b1 + e * IDIM + ib);
    #pragma unroll
    for (int fn = 0; fn < 4; ++fn) {
      const int trow = mt * 256 + wm * 64 + fn * 16 + lr;
      const float v0 = acc[fm][fn][0] + b1v.x;
      const float v1 = acc[fm][fn][1] + b1v.y;
      const float v2 = acc[fm][fn][2] + b1v.z;
      const float v3 = acc[fm][fn][3] + b1v.w;
      ushort4 st;
      st.x = f2b(v0 / (1.f + __expf(-v0)));
      st.y = f2b(v1 / (1.f + __expf(-v1)));
      st.z = f2b(v2 / (1.f + __expf(-v2)));
      st.w = f2b(v3 / (1.f + __expf(-v3)));
      *(ushort4*)(h + (size_t)trow * IDIM + ib) = st;
    }
  }
}

// ---------------- grouped GEMM2: y = h @ W2T^T (bf16 ushort4 stores) ---------
// 128x128 block, 256 thr (4 waves), wave 64x64, ring-3 16KB slots (round-10).
__global__ __launch_bounds__(256, 3) void gemm2_k(
    const unsigned short* __restrict__ h, const unsigned short* __restrict__ w2t,
    const int* __restrict__ meta, unsigned short* __restrict__ y)
{
  const int wg = blockIdx.x;                       // 1152 = 144*8, %8==0
  const int id = (wg & 7) * (1152 / 8) + (wg >> 3);
  const int mt = id >> 3, nt = id & 7;
  if (mt * 128 >= meta[24]) return;
  int e = 0;
  #pragma unroll
  for (int i = 1; i < 8; ++i) if (meta[16 + i] <= mt * 128) e = i;

  extern __shared__ char lds[];
  const int t = threadIdx.x;
  const int w = t >> 6, l = t & 63;
  const int wn = w & 1, wm = w >> 1;

  // A = W2T rows (hcol-dim, nt tile); B = h token rows (mt tile)
  const unsigned short* asrc[2]; const unsigned short* bsrc[2];
  #pragma unroll
  for (int c = 0; c < 2; ++c) {
    const int G = c * 256 + t;
    const int line = G >> 3, q = (G & 7) ^ (line & 7);
    const int row = 2 * line + (q >> 2), g = q & 3;
    asrc[c] = w2t + ((size_t)e * HDIM + nt * 128 + row) * IDIM + g * 8;
    bsrc[c] = h + (size_t)(mt * 128 + row) * IDIM + g * 8;
  }

  const int lr = l & 15, lg = l >> 4;
  f32x4 acc[4][4] = {};

  auto STAGE = [&](int kt) {
    char* sb = lds + (kt % 3) * SLOT2;
    const int ks = kt * 32;
    gld16(asrc[0] + ks, sb + w * 1024);
    gld16(asrc[1] + ks, sb + 4096 + w * 1024);
    gld16(bsrc[0] + ks, sb + 8192 + w * 1024);
    gld16(bsrc[1] + ks, sb + 12288 + w * 1024);
  };

  STAGE(0); STAGE(1);
  const int NT = IDIM / 32;                        // 128
  for (int kt = 0; kt < NT; ++kt) {
    if (kt + 1 < NT) {
      asm volatile("s_waitcnt vmcnt(4)" ::: "memory");
    } else {
      asm volatile("s_waitcnt vmcnt(0)" ::: "memory");
    }
    pinned_barrier();
    const char* sl = lds + (kt % 3) * SLOT2;
    bf16x8 af[4], bf[4];
    #pragma unroll
    for (int f = 0; f < 4; ++f) {
      const int rowA = wn * 64 + f * 16 + lr;
      const int lineA = rowA >> 1;
      const int pA = (((rowA & 1) << 2) + lg) ^ (lineA & 7);
      af[f] = *(const bf16x8*)(sl + lineA * 128 + pA * 16);
      const int rowB = wm * 64 + f * 16 + lr;
      const int lineB = rowB >> 1;
      const int pB = (((rowB & 1) << 2) + lg) ^ (lineB & 7);
      bf[f] = *(const bf16x8*)(sl + 8192 + lineB * 128 + pB * 16);
    }
    if (kt + 2 < NT) STAGE(kt + 2);
    __builtin_amdgcn_s_setprio(1);
    #pragma unroll
    for (int fm = 0; fm < 4; ++fm)
      #pragma unroll
      for (int fn = 0; fn < 4; ++fn)
        acc[fm][fn] = __builtin_amdgcn_mfma_f32_16x16x32_bf16(af[fm], bf[fn], acc[fm][fn], 0, 0, 0);
    __builtin_amdgcn_s_setprio(0);
    pinned_barrier();
  }

  // epilogue: bf16 ushort4 stores (D reg-dim = hcol, col-dim = token)
  const int lg4 = lg * 4;
  #pragma unroll
  for (int fm = 0; fm < 4; ++fm) {
    const int colb = nt * 128 + wn * 64 + fm * 16 + lg4;
    #pragma unroll
    for (int fn = 0; fn < 4; ++fn) {
      const int row = mt * 128 + wm * 64 + fn * 16 + lr;
      ushort4 st;
      st.x = f2b(acc[fm][fn][0]); st.y = f2b(acc[fm][fn][1]);
      st.z = f2b(acc[fm][fn][2]); st.w = f2b(acc[fm][fn][3]);
      *(ushort4*)(y + (size_t)row * HDIM + colb) = st;
    }
  }
}

// ---------------- combine: out[t] = w0*(y[p0]+b2[e0]) + w1*(y[p1]+b2[e1]) ----
__global__ __launch_bounds__(256, 4) void combine_k(
    const unsigned short* __restrict__ y, const float* __restrict__ b2,
    const int* __restrict__ t2e, const float* __restrict__ t2w,
    const int* __restrict__ t2p, float* __restrict__ out)
{
  const int t = blockIdx.x * 4 + (threadIdx.x >> 6);
  const int l = threadIdx.x & 63;
  const int e0 = t2e[t * 2], e1 = t2e[t * 2 + 1];
  const float w0 = t2w[t * 2], w1v = t2w[t * 2 + 1];
  const int p0 = t2p[t * 2], p1 = t2p[t * 2 + 1];
  const unsigned short* y0 = y + (size_t)p0 * HDIM;
  const unsigned short* y1 = y + (size_t)p1 * HDIM;
  const float* bb0 = b2 + e0 * HDIM;
  const float* bb1 = b2 + e1 * HDIM;
  float* o = out + (size_t)t * HDIM;
  #pragma unroll
  for (int j = 0; j < 4; ++j) {
    const int c = j * 256 + l * 4;
    const ushort4 a = *(const ushort4*)(y0 + c);
    const ushort4 b = *(const ushort4*)(y1 + c);
    const float4 c0 = *(const float4*)(bb0 + c);
    const float4 c1 = *(const float4*)(bb1 + c);
    float4 r;
    r.x = w0 * (b2f(a.x) + c0.x) + w1v * (b2f(b.x) + c1.x);
    r.y = w0 * (b2f(a.y) + c0.y) + w1v * (b2f(b.y) + c1.y);
    r.z = w0 * (b2f(a.z) + c0.z) + w1v * (b2f(b.z) + c1.z);
    r.w = w0 * (b2f(a.w) + c0.w) + w1v * (b2f(b.w) + c1.w);
    *(float4*)(o + c) = r;
  }
}

__global__ void sentinel_k(float* out) { out[0] = 1.0e6f; }

// ---------------- launcher ----------------
extern "C" void kernel_launch(void* const* d_in, const int* in_sizes, int n_in,
                              void* d_out, int out_size, void* d_ws, size_t ws_size,
                              hipStream_t stream)
{
  (void)in_sizes; (void)n_in; (void)out_size;
  const float* x  = (const float*)d_in[0];
  const float* wr = (const float*)d_in[1];
  const float* w1 = (const float*)d_in[2];
  const float* b1 = (const float*)d_in[3];
  const float* w2 = (const float*)d_in[4];
  const float* b2 = (const float*)d_in[5];
  float* out = (float*)d_out;
  char* ws = (char*)d_ws;

  if (ws_size < WS_NEED) { sentinel_k<<<1, 1, 0, stream>>>(out); return; }

  unsigned short* xb  = (unsigned short*)(ws);                 // 16.78 MB
  unsigned short* w1t = (unsigned short*)(ws + 16777216);      // 67.1 MB
  unsigned short* w2t = (unsigned short*)(ws + 83886080);      // 67.1 MB
  unsigned short* h   = (unsigned short*)(ws + 150994944);     // 151.0 MB
  int*   t2e  = (int*)(ws + 301989888);
  float* t2w  = (float*)(ws + 302055424);
  int*   ltok = (int*)(ws + 302120960);
  int*   t2p  = (int*)(ws + 302194688);
  int*   meta = (int*)(ws + 302260224);
  // y (bf16) aliases xb+w1t-head (both dead after gemm1): PMAX*HDIM*2 = 37.7MB
  unsigned short* y = (unsigned short*)(ws);

  // allow dynamic LDS on the GEMMs (non-stream op; graph-capture safe)
  hipFuncSetAttribute((const void*)gemm1_k, hipFuncAttributeMaxDynamicSharedMemorySize, 3 * SLOT1);
  hipFuncSetAttribute((const void*)gemm2_k, hipFuncAttributeMaxDynamicSharedMemorySize, 3 * SLOT2);

  // merged router + packT(w1) + packT(w2): 2048 + 4096 + 4096 blocks
  prep_k<<<10240, 256, 0, stream>>>(x, wr, xb, t2e, t2w, w1, w1t, w2, w2t);
  count_k<<<1, 512, 0, stream>>>(t2e, meta);
  scatter_k<<<NEXP, 256, 0, stream>>>(t2e, meta, ltok, t2p);

  gemm1_k<<<72 * 32, 512, 3 * SLOT1, stream>>>(xb, w1t, b1, meta, ltok, h);
  gemm2_k<<<144 * 8, 256, 3 * SLOT2, stream>>>(h, w2t, meta, y);
  combine_k<<<TTOK / 4, 256, 0, stream>>>(y, b2, t2e, t2w, t2p, out);
}